// Round 4
// baseline (150.476 us; speedup 1.0000x reference)
//
#include <hip/hip_runtime.h>
#include <hip/hip_bf16.h>
#include <stdint.h>

typedef unsigned short u16;
typedef __attribute__((ext_vector_type(8))) short short8;
typedef __attribute__((ext_vector_type(8))) __bf16 bf16x8;
typedef __attribute__((ext_vector_type(4))) float f32x4;

constexpr int Bc  = 4;
constexpr int Tc  = 2048;
constexpr int Dc  = 768;
constexpr int Hc  = 12;
constexpr int WINc = 128;

static __device__ __forceinline__ u16 f2bf(float f) {
  union { float f; uint32_t u; } v; v.f = f;
  uint32_t u = v.u;
  return (u16)((u + 0x7fffu + ((u >> 16) & 1u)) >> 16);
}

static __device__ __forceinline__ f32x4 mfma16x16x32(bf16x8 a, bf16x8 b, f32x4 c) {
  return __builtin_amdgcn_mfma_f32_16x16x32_bf16(a, b, c, 0, 0, 0);
}

#define GLOAD_LDS16(gsrc, ldst)                                                \
  __builtin_amdgcn_global_load_lds(                                            \
      (const __attribute__((address_space(1))) void*)(gsrc),                   \
      (__attribute__((address_space(3))) void*)(ldst), 16, 0, 0)

// ---------------------------------------------------------------- cvt x -> bf16
__global__ __launch_bounds__(256) void cvt_f32_to_bf16(const float* __restrict__ in,
                                                       u16* __restrict__ out) {
  const int i = blockIdx.x * 256 + threadIdx.x;
  const float4 f = ((const float4*)in)[i];
  union { u16 h[4]; uint2 u; } pk;
  pk.h[0] = f2bf(f.x); pk.h[1] = f2bf(f.y); pk.h[2] = f2bf(f.z); pk.h[3] = f2bf(f.w);
  ((uint2*)out)[i] = pk.u;
}

// ------------------------------------------- W [R][C] f32  ->  WT [C][R] bf16
__global__ __launch_bounds__(256) void transpose_cvt(const float* __restrict__ W,
                                                     u16* __restrict__ WT,
                                                     int R, int C) {
  __shared__ float tile[64][65];
  const int t  = threadIdx.x;
  const int c0 = blockIdx.x * 64, r0 = blockIdx.y * 64;
#pragma unroll
  for (int i = 0; i < 16; ++i) {
    const int e = i * 256 + t;
    const int r = e >> 6, c = e & 63;
    tile[r][c] = W[(size_t)(r0 + r) * C + c0 + c];
  }
  __syncthreads();
#pragma unroll
  for (int i = 0; i < 16; ++i) {
    const int e = i * 256 + t;
    const int r = e >> 6, c = e & 63;
    WT[(size_t)(c0 + r) * R + r0 + c] = f2bf(tile[c][r]);
  }
}

// ---------------------------------------------------------------- GEMM  C = A * B^T
// R2-proven structure: single-buffered, 2 barriers per K-step, global_load_lds
// width=16 staging (linear LDS layout, wave-uniform dest base). TLP (6 blocks/CU)
// hides the load latency; explicit dbuf regressed (R3 post-mortem).
// EPI==0: q/k row-major [bh][t][64] (q pre-scaled by 0.125), V transposed
//         [bh][d][T] so attention consumes V without any LDS transpose.
// EPI==1: write f32 to out [M][768].
template <int EPI>
__global__ __launch_bounds__(256) void gemm_bt(const u16* __restrict__ A,
                                               const u16* __restrict__ Bt,
                                               u16* __restrict__ q_ws,
                                               u16* __restrict__ k_ws,
                                               u16* __restrict__ v_ws,
                                               float* __restrict__ fout) {
  __shared__ u16 As[128][32];
  __shared__ u16 Bs[128][32];
  const int t  = threadIdx.x;
  const int w  = t >> 6, l = t & 63;
  const int lr = l & 15, lh = l >> 4;
  const int wm = w >> 1, wn = w & 1;
  const int m0 = blockIdx.y * 128, n0 = blockIdx.x * 128;

  f32x4 acc[4][4];
#pragma unroll
  for (int mi = 0; mi < 4; ++mi)
#pragma unroll
    for (int ni = 0; ni < 4; ++ni) acc[mi][ni] = f32x4{0.f, 0.f, 0.f, 0.f};

  const int srow = l >> 2;
  const int scol = (l & 3) * 8;
  const u16* aP = A  + (size_t)(m0 + w * 16 + srow) * 768 + scol;
  const u16* bP = Bt + (size_t)(n0 + w * 16 + srow) * 768 + scol;
  char* asB = (char*)As + w * 1024;
  char* bsB = (char*)Bs + w * 1024;

  for (int kt = 0; kt < 24; ++kt) {
    const int ko = kt * 32;
    __syncthreads();   // previous compute done before overwrite
    GLOAD_LDS16(aP + ko,            asB);
    GLOAD_LDS16(aP + ko + 64 * 768, asB + 4096);
    GLOAD_LDS16(bP + ko,            bsB);
    GLOAD_LDS16(bP + ko + 64 * 768, bsB + 4096);
    __syncthreads();   // compiler drains vmcnt before this barrier

    bf16x8 af[4], bfr[4];
#pragma unroll
    for (int mi = 0; mi < 4; ++mi)
      af[mi] = *(const bf16x8*)&As[wm * 64 + mi * 16 + lr][lh * 8];
#pragma unroll
    for (int ni = 0; ni < 4; ++ni)
      bfr[ni] = *(const bf16x8*)&Bs[wn * 64 + ni * 16 + lr][lh * 8];
#pragma unroll
    for (int mi = 0; mi < 4; ++mi)
#pragma unroll
      for (int ni = 0; ni < 4; ++ni)
        acc[mi][ni] = mfma16x16x32(af[mi], bfr[ni], acc[mi][ni]);
  }

  if (EPI == 0) {
#pragma unroll
    for (int mi = 0; mi < 4; ++mi)
#pragma unroll
      for (int ni = 0; ni < 4; ++ni) {
        const int col   = n0 + wn * 64 + ni * 16 + lr;
        const int which = col / 768;
        const int rem   = col - which * 768;
        const int h     = rem >> 6, d = rem & 63;
#pragma unroll
        for (int r = 0; r < 4; ++r) {
          const int m  = m0 + wm * 64 + mi * 16 + lh * 4 + r;
          const int bb = m >> 11, tt = m & 2047;   // T = 2048
          if (which == 0)       // q, pre-scaled by 1/sqrt(64) (exact in bf16)
            q_ws[(((size_t)(bb * Hc + h) * Tc + tt) << 6) + d] =
                f2bf(acc[mi][ni][r] * 0.125f);
          else if (which == 1)
            k_ws[(((size_t)(bb * Hc + h) * Tc + tt) << 6) + d] =
                f2bf(acc[mi][ni][r]);
          else                  // V stored transposed: [bh][d][T]
            v_ws[(((size_t)((bb * Hc + h) * 64 + d)) << 11) + tt] =
                f2bf(acc[mi][ni][r]);
        }
      }
  } else {
#pragma unroll
    for (int mi = 0; mi < 4; ++mi)
#pragma unroll
      for (int ni = 0; ni < 4; ++ni) {
        const int col = n0 + wn * 64 + ni * 16 + lr;
#pragma unroll
        for (int r = 0; r < 4; ++r) {
          const int m = m0 + wm * 64 + mi * 16 + lh * 4 + r;
          fout[(size_t)m * 768 + col] = acc[mi][ni][r];
        }
      }
  }
}

// ----------------------------------------------- sliding-window flash attention
// Q/K: [bh][T][64] bf16 (q pre-scaled). Vt: [bh][64][T] bf16.
// Barrier-free: every wave owns 16 query rows; fragments loaded DIRECTLY from
// global (K/V per head = 256 KB, L2-resident). Only LDS use: wave-private P tile.
__global__ __launch_bounds__(256) void swa_attn(const u16* __restrict__ Q,
                                                const u16* __restrict__ Kk,
                                                const u16* __restrict__ Vt,
                                                u16* __restrict__ Out) {
  __shared__ u16 Ps[4][16][72];   // per-wave P tile (16 q x 64 k), padded

  const int t  = threadIdx.x;
  const int w  = t >> 6, l = t & 63;
  const int lr = l & 15, lh = l >> 4;
  const int bh = blockIdx.y;
  const int q0 = blockIdx.x * 64 + w * 16;     // this wave's 16 query rows
  const size_t hb  = (size_t)bh * (Tc * 64);   // Q/K base
  const size_t hbv = (size_t)bh * (64 * Tc);   // Vt base

  const bf16x8 qa0 = *(const bf16x8*)(Q + hb + (size_t)(q0 + lr) * 64 + lh * 8);
  const bf16x8 qa1 = *(const bf16x8*)(Q + hb + (size_t)(q0 + lr) * 64 + 32 + lh * 8);

  float m_r[4], l_r[4];
  f32x4 Oa[4];
#pragma unroll
  for (int r = 0; r < 4; ++r) { m_r[r] = -1e30f; l_r[r] = 0.f; }
#pragma unroll
  for (int n = 0; n < 4; ++n) Oa[n] = f32x4{0.f, 0.f, 0.f, 0.f};

  const int kb_lo = (q0 >= WINc) ? ((q0 - WINc) & ~63) : 0;
  const int kb_hi = q0 & ~63;
  for (int kb = kb_lo; kb <= kb_hi; kb += 64) {
    // ---- QK^T on K fragments straight from global
    f32x4 s[4];
#pragma unroll
    for (int sub = 0; sub < 4; ++sub) {
      const u16* kr = Kk + hb + (size_t)(kb + sub * 16 + lr) * 64;
      const bf16x8 kf0 = *(const bf16x8*)(kr + lh * 8);
      const bf16x8 kf1 = *(const bf16x8*)(kr + 32 + lh * 8);
      f32x4 z = f32x4{0.f, 0.f, 0.f, 0.f};
      z = mfma16x16x32(qa0, kf0, z);
      z = mfma16x16x32(qa1, kf1, z);
      s[sub] = z;
    }

    // ---- prefetch V fragments (independent of softmax; hides L2 latency)
    bf16x8 vf[2][4];
#pragma unroll
    for (int ks = 0; ks < 2; ++ks)
#pragma unroll
      for (int ni = 0; ni < 4; ++ni)
        vf[ks][ni] = *(const bf16x8*)(Vt + hbv + (size_t)(ni * 16 + lr) * Tc
                                      + kb + ks * 32 + lh * 8);

    // ---- mask (allowed: qi-128 <= kj <= qi); scale already folded into Q
    const int qbase = q0 + lh * 4;
#pragma unroll
    for (int sub = 0; sub < 4; ++sub) {
      const int kj = kb + sub * 16 + lr;
#pragma unroll
      for (int r = 0; r < 4; ++r) {
        const int qi = qbase + r;
        const bool ok = (kj <= qi) && (kj + WINc >= qi);
        s[sub][r] = ok ? s[sub][r] : -1e30f;
      }
    }

    // ---- online softmax (row = reduce across the 16-lane lr group)
    float mt[4];
#pragma unroll
    for (int r = 0; r < 4; ++r)
      mt[r] = fmaxf(fmaxf(s[0][r], s[1][r]), fmaxf(s[2][r], s[3][r]));
#pragma unroll
    for (int msk = 1; msk < 16; msk <<= 1)
#pragma unroll
      for (int r = 0; r < 4; ++r)
        mt[r] = fmaxf(mt[r], __shfl_xor(mt[r], msk, 64));

    float al[4];
#pragma unroll
    for (int r = 0; r < 4; ++r) {
      const float mn = fmaxf(m_r[r], mt[r]);
      al[r] = __expf(m_r[r] - mn);
      m_r[r] = mn;
    }

    float rs[4] = {0.f, 0.f, 0.f, 0.f};
#pragma unroll
    for (int sub = 0; sub < 4; ++sub)
#pragma unroll
      for (int r = 0; r < 4; ++r) {
        const float pv = __expf(s[sub][r] - m_r[r]);
        s[sub][r] = pv;
        rs[r] += pv;
      }
#pragma unroll
    for (int msk = 1; msk < 16; msk <<= 1)
#pragma unroll
      for (int r = 0; r < 4; ++r)
        rs[r] += __shfl_xor(rs[r], msk, 64);
#pragma unroll
    for (int r = 0; r < 4; ++r) l_r[r] = l_r[r] * al[r] + rs[r];

#pragma unroll
    for (int n = 0; n < 4; ++n)
#pragma unroll
      for (int r = 0; r < 4; ++r) Oa[n][r] *= al[r];

    // ---- P -> wave-private LDS (re-layout for PV A-operand); no barrier needed
#pragma unroll
    for (int sub = 0; sub < 4; ++sub)
#pragma unroll
      for (int r = 0; r < 4; ++r)
        Ps[w][lh * 4 + r][sub * 16 + lr] = f2bf(s[sub][r]);

    // ---- PV: O += P (16x64) * V (64x64)
#pragma unroll
    for (int ks = 0; ks < 2; ++ks) {
      const bf16x8 pa = *(const bf16x8*)&Ps[w][lr][ks * 32 + lh * 8];
#pragma unroll
      for (int ni = 0; ni < 4; ++ni)
        Oa[ni] = mfma16x16x32(pa, vf[ks][ni], Oa[ni]);
    }
  }

  // epilogue: write attn out [B][T][H*64] bf16
  const int bb = bh / Hc, h = bh - bb * Hc;
#pragma unroll
  for (int r = 0; r < 4; ++r) {
    const float inv = 1.f / l_r[r];
    const int ti = q0 + lh * 4 + r;
#pragma unroll
    for (int ni = 0; ni < 4; ++ni)
      Out[((size_t)(bb * Tc + ti)) * 768 + h * 64 + ni * 16 + lr] =
          f2bf(Oa[ni][r] * inv);
  }
}

// -----------------------------------------------------------------------------
extern "C" void kernel_launch(void* const* d_in, const int* in_sizes, int n_in,
                              void* d_out, int out_size, void* d_ws, size_t ws_size,
                              hipStream_t stream) {
  (void)in_sizes; (void)n_in; (void)out_size; (void)ws_size;
  const float* x    = (const float*)d_in[0];
  const float* Wqkv = (const float*)d_in[1];
  const float* Wout = (const float*)d_in[2];
  float* out = (float*)d_out;

  u16* ws    = (u16*)d_ws;
  u16* xb    = ws;                     // 6291456 elems (x as bf16)
  u16* wqkvT = xb + 6291456;           // 1769472
  u16* woutT = wqkvT + 1769472;        // 589824
  u16* qws   = woutT + 589824;         // 6291456
  u16* kws   = qws + 6291456;          // 6291456
  u16* vtws  = kws + 6291456;          // 6291456 (transposed layout)
  u16* aws   = xb;                     // attn out aliases xb (dead after gemm1)

  cvt_f32_to_bf16<<<6144, 256, 0, stream>>>(x, xb);
  transpose_cvt<<<dim3(36, 12), 256, 0, stream>>>(Wqkv, wqkvT, 768, 2304);
  transpose_cvt<<<dim3(12, 12), 256, 0, stream>>>(Wout, woutT, 768, 768);
  gemm_bt<0><<<dim3(18, 64), 256, 0, stream>>>(xb, wqkvT, qws, kws, vtws, nullptr);
  swa_attn<<<dim3(32, 48), 256, 0, stream>>>(qws, kws, vtws, aws);
  gemm_bt<1><<<dim3(6, 64), 256, 0, stream>>>(aws, woutT, nullptr, nullptr, nullptr, out);
}

// Round 5
// 134.203 us; speedup vs baseline: 1.1213x; 1.1213x over previous
//
#include <hip/hip_runtime.h>
#include <hip/hip_bf16.h>
#include <stdint.h>

typedef unsigned short u16;
typedef __attribute__((ext_vector_type(8))) short short8;
typedef __attribute__((ext_vector_type(8))) __bf16 bf16x8;
typedef __attribute__((ext_vector_type(4))) float f32x4;

constexpr int Bc  = 4;
constexpr int Tc  = 2048;
constexpr int Dc  = 768;
constexpr int Hc  = 12;
constexpr int WINc = 128;

static __device__ __forceinline__ u16 f2bf(float f) {
  union { float f; uint32_t u; } v; v.f = f;
  uint32_t u = v.u;
  return (u16)((u + 0x7fffu + ((u >> 16) & 1u)) >> 16);
}

static __device__ __forceinline__ f32x4 mfma16x16x32(bf16x8 a, bf16x8 b, f32x4 c) {
  return __builtin_amdgcn_mfma_f32_16x16x32_bf16(a, b, c, 0, 0, 0);
}

#define GLOAD_LDS16(gsrc, ldst)                                                \
  __builtin_amdgcn_global_load_lds(                                            \
      (const __attribute__((address_space(1))) void*)(gsrc),                   \
      (__attribute__((address_space(3))) void*)(ldst), 16, 0, 0)

// ---------------------------------------------------------------- cvt x -> bf16
__global__ __launch_bounds__(256) void cvt_f32_to_bf16(const float* __restrict__ in,
                                                       u16* __restrict__ out) {
  const int i = blockIdx.x * 256 + threadIdx.x;
  const float4 f = ((const float4*)in)[i];
  union { u16 h[4]; uint2 u; } pk;
  pk.h[0] = f2bf(f.x); pk.h[1] = f2bf(f.y); pk.h[2] = f2bf(f.z); pk.h[3] = f2bf(f.w);
  ((uint2*)out)[i] = pk.u;
}

// ------------------------------------------- W [R][C] f32  ->  WT [C][R] bf16
__global__ __launch_bounds__(256) void transpose_cvt(const float* __restrict__ W,
                                                     u16* __restrict__ WT,
                                                     int R, int C) {
  __shared__ float tile[64][65];
  const int t  = threadIdx.x;
  const int c0 = blockIdx.x * 64, r0 = blockIdx.y * 64;
#pragma unroll
  for (int i = 0; i < 16; ++i) {
    const int e = i * 256 + t;
    const int r = e >> 6, c = e & 63;
    tile[r][c] = W[(size_t)(r0 + r) * C + c0 + c];
  }
  __syncthreads();
#pragma unroll
  for (int i = 0; i < 16; ++i) {
    const int e = i * 256 + t;
    const int r = e >> 6, c = e & 63;
    WT[(size_t)(c0 + r) * R + r0 + c] = f2bf(tile[c][r]);
  }
}

// --------------------------------- V [bh][t][64] bf16 -> Vt [bh][64][T] bf16
// 64x64 tile through XOR-swizzled LDS (col ^= ((row>>4)&3)<<4): load and store
// both coalesced (128 B/row); LDS both sides 2-way conflict only (free, m136).
__global__ __launch_bounds__(256) void v_transpose(const u16* __restrict__ V,
                                                   u16* __restrict__ Vt) {
  __shared__ u16 tile[64][72];
  const int t  = threadIdx.x;
  const int bh = blockIdx.y;
  const int t0 = blockIdx.x * 64;
  const size_t ib = (size_t)bh * Tc * 64;
  const size_t ob = (size_t)bh * 64 * Tc;
  {
    const int row  = t >> 2;
    const int colg = (t & 3) * 16;
    const int cols = colg ^ (((row >> 4) & 3) << 4);
    const short8* src = (const short8*)(V + ib + (size_t)(t0 + row) * 64 + colg);
    *(short8*)&tile[row][cols]     = src[0];
    *(short8*)&tile[row][cols + 8] = src[1];
  }
  __syncthreads();
  {
    const int d = t >> 2, c = t & 3;
    const int colr = d ^ (c << 4);   // (row>>4)&3 == c for rows c*16+j, j<16
    union { u16 h[16]; short8 v[2]; } o;
#pragma unroll
    for (int j = 0; j < 16; ++j) o.h[j] = tile[c * 16 + j][colr];
    short8* dst = (short8*)(Vt + ob + (size_t)d * Tc + t0 + c * 16);
    dst[0] = o.v[0];
    dst[1] = o.v[1];
  }
}

// ---------------------------------------------------------------- GEMM  C = A * B^T
// R2-proven structure: single-buffered, 2 barriers per K-step, global_load_lds
// width=16 staging, linear LDS. TLP (6 blocks/CU @ VGPR<=84) hides load latency.
// EPI==0: q/k/v ALL row-major [bh][t][64] coalesced (q pre-scaled by 0.125).
// EPI==1: write f32 to out [M][768].
template <int EPI>
__global__ __launch_bounds__(256) void gemm_bt(const u16* __restrict__ A,
                                               const u16* __restrict__ Bt,
                                               u16* __restrict__ q_ws,
                                               u16* __restrict__ k_ws,
                                               u16* __restrict__ v_ws,
                                               float* __restrict__ fout) {
  __shared__ u16 As[128][32];
  __shared__ u16 Bs[128][32];
  const int t  = threadIdx.x;
  const int w  = t >> 6, l = t & 63;
  const int lr = l & 15, lh = l >> 4;
  const int wm = w >> 1, wn = w & 1;
  const int m0 = blockIdx.y * 128, n0 = blockIdx.x * 128;

  f32x4 acc[4][4];
#pragma unroll
  for (int mi = 0; mi < 4; ++mi)
#pragma unroll
    for (int ni = 0; ni < 4; ++ni) acc[mi][ni] = f32x4{0.f, 0.f, 0.f, 0.f};

  const int srow = l >> 2;
  const int scol = (l & 3) * 8;
  const u16* aP = A  + (size_t)(m0 + w * 16 + srow) * 768 + scol;
  const u16* bP = Bt + (size_t)(n0 + w * 16 + srow) * 768 + scol;
  char* asB = (char*)As + w * 1024;
  char* bsB = (char*)Bs + w * 1024;

  for (int kt = 0; kt < 24; ++kt) {
    const int ko = kt * 32;
    __syncthreads();   // previous compute done before overwrite
    GLOAD_LDS16(aP + ko,            asB);
    GLOAD_LDS16(aP + ko + 64 * 768, asB + 4096);
    GLOAD_LDS16(bP + ko,            bsB);
    GLOAD_LDS16(bP + ko + 64 * 768, bsB + 4096);
    __syncthreads();   // compiler drains vmcnt before this barrier

    bf16x8 af[4], bfr[4];
#pragma unroll
    for (int mi = 0; mi < 4; ++mi)
      af[mi] = *(const bf16x8*)&As[wm * 64 + mi * 16 + lr][lh * 8];
#pragma unroll
    for (int ni = 0; ni < 4; ++ni)
      bfr[ni] = *(const bf16x8*)&Bs[wn * 64 + ni * 16 + lr][lh * 8];
#pragma unroll
    for (int mi = 0; mi < 4; ++mi)
#pragma unroll
      for (int ni = 0; ni < 4; ++ni)
        acc[mi][ni] = mfma16x16x32(af[mi], bfr[ni], acc[mi][ni]);
  }

  if (EPI == 0) {
#pragma unroll
    for (int mi = 0; mi < 4; ++mi)
#pragma unroll
      for (int ni = 0; ni < 4; ++ni) {
        const int col   = n0 + wn * 64 + ni * 16 + lr;
        const int which = col / 768;
        const int rem   = col - which * 768;
        const int h     = rem >> 6, d = rem & 63;
        u16* dst = (which == 0) ? q_ws : ((which == 1) ? k_ws : v_ws);
        const float scl = (which == 0) ? 0.125f : 1.0f;   // fold 1/sqrt(64) into q
#pragma unroll
        for (int r = 0; r < 4; ++r) {
          const int m  = m0 + wm * 64 + mi * 16 + lh * 4 + r;
          const int bb = m >> 11, tt = m & 2047;   // T = 2048
          dst[(((size_t)(bb * Hc + h) * Tc + tt) << 6) + d] = f2bf(acc[mi][ni][r] * scl);
        }
      }
  } else {
#pragma unroll
    for (int mi = 0; mi < 4; ++mi)
#pragma unroll
      for (int ni = 0; ni < 4; ++ni) {
        const int col = n0 + wn * 64 + ni * 16 + lr;
#pragma unroll
        for (int r = 0; r < 4; ++r) {
          const int m = m0 + wm * 64 + mi * 16 + lh * 4 + r;
          fout[(size_t)m * 768 + col] = acc[mi][ni][r];
        }
      }
  }
}

// ----------------------------------------------- sliding-window flash attention
// Q/K: [bh][T][64] bf16 (q pre-scaled). Vt: [bh][64][T] bf16.
// Barrier-free: every wave owns 16 query rows; fragments loaded DIRECTLY from
// global (K/V per head = 256 KB, L2-resident). Only LDS use: wave-private P tile.
__global__ __launch_bounds__(256) void swa_attn(const u16* __restrict__ Q,
                                                const u16* __restrict__ Kk,
                                                const u16* __restrict__ Vt,
                                                u16* __restrict__ Out) {
  __shared__ u16 Ps[4][16][72];   // per-wave P tile (16 q x 64 k), padded

  const int t  = threadIdx.x;
  const int w  = t >> 6, l = t & 63;
  const int lr = l & 15, lh = l >> 4;
  const int bh = blockIdx.y;
  const int q0 = blockIdx.x * 64 + w * 16;     // this wave's 16 query rows
  const size_t hb  = (size_t)bh * (Tc * 64);   // Q/K base
  const size_t hbv = (size_t)bh * (64 * Tc);   // Vt base

  const bf16x8 qa0 = *(const bf16x8*)(Q + hb + (size_t)(q0 + lr) * 64 + lh * 8);
  const bf16x8 qa1 = *(const bf16x8*)(Q + hb + (size_t)(q0 + lr) * 64 + 32 + lh * 8);

  float m_r[4], l_r[4];
  f32x4 Oa[4];
#pragma unroll
  for (int r = 0; r < 4; ++r) { m_r[r] = -1e30f; l_r[r] = 0.f; }
#pragma unroll
  for (int n = 0; n < 4; ++n) Oa[n] = f32x4{0.f, 0.f, 0.f, 0.f};

  const int kb_lo = (q0 >= WINc) ? ((q0 - WINc) & ~63) : 0;
  const int kb_hi = q0 & ~63;
  for (int kb = kb_lo; kb <= kb_hi; kb += 64) {
    // ---- QK^T on K fragments straight from global
    f32x4 s[4];
#pragma unroll
    for (int sub = 0; sub < 4; ++sub) {
      const u16* kr = Kk + hb + (size_t)(kb + sub * 16 + lr) * 64;
      const bf16x8 kf0 = *(const bf16x8*)(kr + lh * 8);
      const bf16x8 kf1 = *(const bf16x8*)(kr + 32 + lh * 8);
      f32x4 z = f32x4{0.f, 0.f, 0.f, 0.f};
      z = mfma16x16x32(qa0, kf0, z);
      z = mfma16x16x32(qa1, kf1, z);
      s[sub] = z;
    }

    // ---- prefetch V fragments (independent of softmax; hides L2 latency)
    bf16x8 vf[2][4];
#pragma unroll
    for (int ks = 0; ks < 2; ++ks)
#pragma unroll
      for (int ni = 0; ni < 4; ++ni)
        vf[ks][ni] = *(const bf16x8*)(Vt + hbv + (size_t)(ni * 16 + lr) * Tc
                                      + kb + ks * 32 + lh * 8);

    // ---- mask (allowed: qi-128 <= kj <= qi); scale already folded into Q
    const int qbase = q0 + lh * 4;
#pragma unroll
    for (int sub = 0; sub < 4; ++sub) {
      const int kj = kb + sub * 16 + lr;
#pragma unroll
      for (int r = 0; r < 4; ++r) {
        const int qi = qbase + r;
        const bool ok = (kj <= qi) && (kj + WINc >= qi);
        s[sub][r] = ok ? s[sub][r] : -1e30f;
      }
    }

    // ---- online softmax (row = reduce across the 16-lane lr group)
    float mt[4];
#pragma unroll
    for (int r = 0; r < 4; ++r)
      mt[r] = fmaxf(fmaxf(s[0][r], s[1][r]), fmaxf(s[2][r], s[3][r]));
#pragma unroll
    for (int msk = 1; msk < 16; msk <<= 1)
#pragma unroll
      for (int r = 0; r < 4; ++r)
        mt[r] = fmaxf(mt[r], __shfl_xor(mt[r], msk, 64));

    float al[4];
#pragma unroll
    for (int r = 0; r < 4; ++r) {
      const float mn = fmaxf(m_r[r], mt[r]);
      al[r] = __expf(m_r[r] - mn);
      m_r[r] = mn;
    }

    float rs[4] = {0.f, 0.f, 0.f, 0.f};
#pragma unroll
    for (int sub = 0; sub < 4; ++sub)
#pragma unroll
      for (int r = 0; r < 4; ++r) {
        const float pv = __expf(s[sub][r] - m_r[r]);
        s[sub][r] = pv;
        rs[r] += pv;
      }
#pragma unroll
    for (int msk = 1; msk < 16; msk <<= 1)
#pragma unroll
      for (int r = 0; r < 4; ++r)
        rs[r] += __shfl_xor(rs[r], msk, 64);
#pragma unroll
    for (int r = 0; r < 4; ++r) l_r[r] = l_r[r] * al[r] + rs[r];

#pragma unroll
    for (int n = 0; n < 4; ++n)
#pragma unroll
      for (int r = 0; r < 4; ++r) Oa[n][r] *= al[r];

    // ---- P -> wave-private LDS (re-layout for PV A-operand); no barrier needed
#pragma unroll
    for (int sub = 0; sub < 4; ++sub)
#pragma unroll
      for (int r = 0; r < 4; ++r)
        Ps[w][lh * 4 + r][sub * 16 + lr] = f2bf(s[sub][r]);

    // ---- PV: O += P (16x64) * V (64x64)
#pragma unroll
    for (int ks = 0; ks < 2; ++ks) {
      const bf16x8 pa = *(const bf16x8*)&Ps[w][lr][ks * 32 + lh * 8];
#pragma unroll
      for (int ni = 0; ni < 4; ++ni)
        Oa[ni] = mfma16x16x32(pa, vf[ks][ni], Oa[ni]);
    }
  }

  // epilogue: write attn out [B][T][H*64] bf16
  const int bb = bh / Hc, h = bh - bb * Hc;
#pragma unroll
  for (int r = 0; r < 4; ++r) {
    const float inv = 1.f / l_r[r];
    const int ti = q0 + lh * 4 + r;
#pragma unroll
    for (int ni = 0; ni < 4; ++ni)
      Out[((size_t)(bb * Tc + ti)) * 768 + h * 64 + ni * 16 + lr] =
          f2bf(Oa[ni][r] * inv);
  }
}

// -----------------------------------------------------------------------------
extern "C" void kernel_launch(void* const* d_in, const int* in_sizes, int n_in,
                              void* d_out, int out_size, void* d_ws, size_t ws_size,
                              hipStream_t stream) {
  (void)in_sizes; (void)n_in; (void)out_size; (void)ws_size;
  const float* x    = (const float*)d_in[0];
  const float* Wqkv = (const float*)d_in[1];
  const float* Wout = (const float*)d_in[2];
  float* out = (float*)d_out;

  // ws aliasing plan (u16 elems):
  //   xb    [0, 6.29M)  : x bf16 (dead after gemm1)  -> reused as vtws
  //   wqkvT, woutT      : weights
  //   qws, kws, vws     : gemm1 outputs (vws row-major, dead after v_transpose)
  //   vtws = xb         : transposed V, read by attn
  //   aws  = vws        : attn out, read by gemm2
  u16* ws    = (u16*)d_ws;
  u16* xb    = ws;                     // 6291456
  u16* wqkvT = xb + 6291456;           // 1769472
  u16* woutT = wqkvT + 1769472;        // 589824
  u16* qws   = woutT + 589824;         // 6291456
  u16* kws   = qws + 6291456;          // 6291456
  u16* vws   = kws + 6291456;          // 6291456
  u16* vtws  = xb;                     // aliases xb (x dead after gemm1)
  u16* aws   = vws;                    // aliases vws (dead after v_transpose)

  cvt_f32_to_bf16<<<6144, 256, 0, stream>>>(x, xb);
  transpose_cvt<<<dim3(36, 12), 256, 0, stream>>>(Wqkv, wqkvT, 768, 2304);
  transpose_cvt<<<dim3(12, 12), 256, 0, stream>>>(Wout, woutT, 768, 768);
  gemm_bt<0><<<dim3(18, 64), 256, 0, stream>>>(xb, wqkvT, qws, kws, vws, nullptr);
  v_transpose<<<dim3(32, 48), 256, 0, stream>>>(vws, vtws);
  swa_attn<<<dim3(32, 48), 256, 0, stream>>>(qws, kws, vtws, aws);
  gemm_bt<1><<<dim3(6, 64), 256, 0, stream>>>(aws, woutT, nullptr, nullptr, nullptr, out);
}

// Round 6
// 110.731 us; speedup vs baseline: 1.3589x; 1.2120x over previous
//
#include <hip/hip_runtime.h>
#include <hip/hip_bf16.h>
#include <stdint.h>

typedef unsigned short u16;
typedef __attribute__((ext_vector_type(8))) short short8;
typedef __attribute__((ext_vector_type(8))) __bf16 bf16x8;
typedef __attribute__((ext_vector_type(4))) float f32x4;

constexpr int Bc  = 4;
constexpr int Tc  = 2048;
constexpr int Dc  = 768;
constexpr int Hc  = 12;
constexpr int WINc = 128;

static __device__ __forceinline__ u16 f2bf(float f) {
  union { float f; uint32_t u; } v; v.f = f;
  uint32_t u = v.u;
  return (u16)((u + 0x7fffu + ((u >> 16) & 1u)) >> 16);
}

static __device__ __forceinline__ f32x4 mfma16x16x32(bf16x8 a, bf16x8 b, f32x4 c) {
  return __builtin_amdgcn_mfma_f32_16x16x32_bf16(a, b, c, 0, 0, 0);
}

#define GLOAD_LDS16(gsrc, ldst)                                                \
  __builtin_amdgcn_global_load_lds(                                            \
      (const __attribute__((address_space(1))) void*)(gsrc),                   \
      (__attribute__((address_space(3))) void*)(ldst), 16, 0, 0)

// ---------------------------------------------------------------- cvt x -> bf16
__global__ __launch_bounds__(256) void cvt_f32_to_bf16(const float* __restrict__ in,
                                                       u16* __restrict__ out) {
  const int i = blockIdx.x * 256 + threadIdx.x;
  const float4 f = ((const float4*)in)[i];
  union { u16 h[4]; uint2 u; } pk;
  pk.h[0] = f2bf(f.x); pk.h[1] = f2bf(f.y); pk.h[2] = f2bf(f.z); pk.h[3] = f2bf(f.w);
  ((uint2*)out)[i] = pk.u;
}

// ------------------------------------------- W [R][C] f32  ->  WT [C][R] bf16
__global__ __launch_bounds__(256) void transpose_cvt(const float* __restrict__ W,
                                                     u16* __restrict__ WT,
                                                     int R, int C) {
  __shared__ float tile[64][65];
  const int t  = threadIdx.x;
  const int c0 = blockIdx.x * 64, r0 = blockIdx.y * 64;
#pragma unroll
  for (int i = 0; i < 16; ++i) {
    const int e = i * 256 + t;
    const int r = e >> 6, c = e & 63;
    tile[r][c] = W[(size_t)(r0 + r) * C + c0 + c];
  }
  __syncthreads();
#pragma unroll
  for (int i = 0; i < 16; ++i) {
    const int e = i * 256 + t;
    const int r = e >> 6, c = e & 63;
    WT[(size_t)(c0 + r) * R + r0 + c] = f2bf(tile[c][r]);
  }
}

// ---------------------------------------------------------------- GEMM  C = A * B^T
// BK=64 variant: 12 K-steps (halved barrier/drain count vs BK=32).
// LDS tiles [128][64] u16 with XOR swizzle: logical (row, colbyte) stored at
// row*128 + (colbyte ^ ((row&7)<<4)). global_load_lds writes linearly; the
// per-lane GLOBAL source is inverse-swizzled (both-sides rule), fragment reads
// apply the same XOR -> <=2-way bank conflicts.
// EPI==0: q/k/v row-major [bh][t][64] coalesced (q pre-scaled by 0.125).
// EPI==1: write f32 to out [M][768].
template <int EPI>
__global__ __launch_bounds__(256) void gemm_bt(const u16* __restrict__ A,
                                               const u16* __restrict__ Bt,
                                               u16* __restrict__ q_ws,
                                               u16* __restrict__ k_ws,
                                               u16* __restrict__ v_ws,
                                               float* __restrict__ fout) {
  __shared__ u16 As[128][64];   // 16 KB each
  __shared__ u16 Bs[128][64];
  const int t  = threadIdx.x;
  const int w  = t >> 6, l = t & 63;
  const int lr = l & 15, lh = l >> 4;
  const int wm = w >> 1, wn = w & 1;
  const int m0 = blockIdx.y * 128, n0 = blockIdx.x * 128;

  f32x4 acc[4][4];
#pragma unroll
  for (int mi = 0; mi < 4; ++mi)
#pragma unroll
    for (int ni = 0; ni < 4; ++ni) acc[mi][ni] = f32x4{0.f, 0.f, 0.f, 0.f};

  // staging: LDS byte = j*4096 + w*1024 + l*16  ->  row = j*32+w*8+(l>>3),
  // swz colbyte = (l&7)*16; logical col u16 = ((l&7)^(l>>3))*8 (row&7 == l>>3).
  const int srow = w * 8 + (l >> 3);
  const int scol = ((l & 7) ^ (l >> 3)) * 8;
  const u16* aP = A  + (size_t)(m0 + srow) * 768 + scol;
  const u16* bP = Bt + (size_t)(n0 + srow) * 768 + scol;
  char* asB = (char*)As + w * 1024;
  char* bsB = (char*)Bs + w * 1024;

  for (int kt = 0; kt < 12; ++kt) {
    const int ko = kt * 64;
    __syncthreads();   // previous compute done before overwrite
#pragma unroll
    for (int j = 0; j < 4; ++j) {
      GLOAD_LDS16(aP + ko + j * (32 * 768), asB + j * 4096);
      GLOAD_LDS16(bP + ko + j * (32 * 768), bsB + j * 4096);
    }
    __syncthreads();   // compiler drains vmcnt before this barrier

#pragma unroll
    for (int kk = 0; kk < 2; ++kk) {
      const int cb = (kk * 64 + lh * 16) ^ ((lr & 7) << 4);   // swizzled read col
      bf16x8 af[4], bfr[4];
#pragma unroll
      for (int mi = 0; mi < 4; ++mi)
        af[mi] = *(const bf16x8*)((const char*)As + (wm * 64 + mi * 16 + lr) * 128 + cb);
#pragma unroll
      for (int ni = 0; ni < 4; ++ni)
        bfr[ni] = *(const bf16x8*)((const char*)Bs + (wn * 64 + ni * 16 + lr) * 128 + cb);
#pragma unroll
      for (int mi = 0; mi < 4; ++mi)
#pragma unroll
        for (int ni = 0; ni < 4; ++ni)
          acc[mi][ni] = mfma16x16x32(af[mi], bfr[ni], acc[mi][ni]);
    }
  }

  if (EPI == 0) {
#pragma unroll
    for (int mi = 0; mi < 4; ++mi)
#pragma unroll
      for (int ni = 0; ni < 4; ++ni) {
        const int col   = n0 + wn * 64 + ni * 16 + lr;
        const int which = col / 768;
        const int rem   = col - which * 768;
        const int h     = rem >> 6, d = rem & 63;
        u16* dst = (which == 0) ? q_ws : ((which == 1) ? k_ws : v_ws);
        const float scl = (which == 0) ? 0.125f : 1.0f;   // fold 1/sqrt(64) into q
#pragma unroll
        for (int r = 0; r < 4; ++r) {
          const int m  = m0 + wm * 64 + mi * 16 + lh * 4 + r;
          const int bb = m >> 11, tt = m & 2047;   // T = 2048
          dst[(((size_t)(bb * Hc + h) * Tc + tt) << 6) + d] = f2bf(acc[mi][ni][r] * scl);
        }
      }
  } else {
#pragma unroll
    for (int mi = 0; mi < 4; ++mi)
#pragma unroll
      for (int ni = 0; ni < 4; ++ni) {
        const int col = n0 + wn * 64 + ni * 16 + lr;
#pragma unroll
        for (int r = 0; r < 4; ++r) {
          const int m = m0 + wm * 64 + mi * 16 + lh * 4 + r;
          fout[(size_t)m * 768 + col] = acc[mi][ni][r];
        }
      }
  }
}

// ----------------------------------------------- sliding-window flash attention
// R2-proven staged structure (measured 13 µs faster than de-staged).
// Q/K/V ws: [bh][T][64] bf16 (q pre-scaled by 0.125). Out: [B][T][768] bf16.
// Block = 256 threads (4 waves), one (b,h), 64 queries; K-tiles of 64.
__global__ __launch_bounds__(256) void swa_attn(const u16* __restrict__ Q,
                                                const u16* __restrict__ Kk,
                                                const u16* __restrict__ V,
                                                u16* __restrict__ Out) {
  __shared__ u16 Qs[64][72];
  __shared__ u16 Ks[64][72];
  __shared__ u16 Vt[64][72];      // V transposed: Vt[d][key]
  __shared__ u16 Ps[4][16][72];   // per-wave P tile (16 q x 64 k)

  const int t  = threadIdx.x;
  const int w  = t >> 6, l = t & 63;
  const int lr = l & 15, lh = l >> 4;
  const int bh = blockIdx.y;
  const int q0 = blockIdx.x * 64;
  const size_t head_base = (size_t)bh * Tc * 64;

  {  // stage Q (64 rows x 64 cols)
    const int row = t >> 2, c = (t & 3) * 16;
    const short8* src = (const short8*)(Q + head_base + (size_t)(q0 + row) * 64 + c);
    *(short8*)&Qs[row][c]     = src[0];
    *(short8*)&Qs[row][c + 8] = src[1];
  }

  float m_r[4], l_r[4];
  f32x4 Oa[4];
#pragma unroll
  for (int r = 0; r < 4; ++r) { m_r[r] = -1e30f; l_r[r] = 0.f; }
#pragma unroll
  for (int n = 0; n < 4; ++n) Oa[n] = f32x4{0.f, 0.f, 0.f, 0.f};

  const int kb_lo = (q0 >= WINc) ? q0 - WINc : 0;
  for (int kb = kb_lo; kb <= q0; kb += 64) {
    __syncthreads();   // also covers Q-staging visibility on first iter
    {  // stage K tile and V tile (transposed into Vt)
      const int row = t >> 2, c = (t & 3) * 16;
      const short8* ksrc = (const short8*)(Kk + head_base + (size_t)(kb + row) * 64 + c);
      *(short8*)&Ks[row][c]     = ksrc[0];
      *(short8*)&Ks[row][c + 8] = ksrc[1];
      const short8* vsrc = (const short8*)(V + head_base + (size_t)(kb + row) * 64 + c);
      short8 v0 = vsrc[0], v1 = vsrc[1];
#pragma unroll
      for (int j = 0; j < 8; ++j) {
        Vt[c + j][row]     = (u16)v0[j];
        Vt[c + 8 + j][row] = (u16)v1[j];
      }
    }
    __syncthreads();

    bf16x8 qa0 = *(const bf16x8*)&Qs[w * 16 + lr][lh * 8];
    bf16x8 qa1 = *(const bf16x8*)&Qs[w * 16 + lr][32 + lh * 8];

    f32x4 s[4];
#pragma unroll
    for (int sub = 0; sub < 4; ++sub) {
      bf16x8 kb0 = *(const bf16x8*)&Ks[sub * 16 + lr][lh * 8];
      bf16x8 kb1 = *(const bf16x8*)&Ks[sub * 16 + lr][32 + lh * 8];
      f32x4 z = f32x4{0.f, 0.f, 0.f, 0.f};
      z = mfma16x16x32(qa0, kb0, z);
      z = mfma16x16x32(qa1, kb1, z);
      s[sub] = z;
    }

    // mask (allowed: qi-128 <= kj <= qi); scale pre-folded into Q
    const int qbase = q0 + w * 16 + lh * 4;
#pragma unroll
    for (int sub = 0; sub < 4; ++sub) {
      const int kj = kb + sub * 16 + lr;
#pragma unroll
      for (int r = 0; r < 4; ++r) {
        const int qi = qbase + r;
        const bool ok = (kj <= qi) && (kj + WINc >= qi);
        s[sub][r] = ok ? s[sub][r] : -1e30f;
      }
    }

    // row max across 64 keys of this tile
    float mt[4];
#pragma unroll
    for (int r = 0; r < 4; ++r)
      mt[r] = fmaxf(fmaxf(s[0][r], s[1][r]), fmaxf(s[2][r], s[3][r]));
#pragma unroll
    for (int msk = 1; msk < 16; msk <<= 1)
#pragma unroll
      for (int r = 0; r < 4; ++r)
        mt[r] = fmaxf(mt[r], __shfl_xor(mt[r], msk, 64));

    float al[4];
#pragma unroll
    for (int r = 0; r < 4; ++r) {
      const float mn = fmaxf(m_r[r], mt[r]);
      al[r] = __expf(m_r[r] - mn);
      m_r[r] = mn;
    }

    // p = exp(s - m), row sum
    float rs[4] = {0.f, 0.f, 0.f, 0.f};
#pragma unroll
    for (int sub = 0; sub < 4; ++sub)
#pragma unroll
      for (int r = 0; r < 4; ++r) {
        const float p = __expf(s[sub][r] - m_r[r]);
        s[sub][r] = p;
        rs[r] += p;
      }
#pragma unroll
    for (int msk = 1; msk < 16; msk <<= 1)
#pragma unroll
      for (int r = 0; r < 4; ++r)
        rs[r] += __shfl_xor(rs[r], msk, 64);
#pragma unroll
    for (int r = 0; r < 4; ++r) l_r[r] = l_r[r] * al[r] + rs[r];

    // rescale O
#pragma unroll
    for (int n = 0; n < 4; ++n)
#pragma unroll
      for (int r = 0; r < 4; ++r) Oa[n][r] *= al[r];

    // P -> LDS (wave-private), re-layout for PV A-operand
#pragma unroll
    for (int sub = 0; sub < 4; ++sub)
#pragma unroll
      for (int r = 0; r < 4; ++r)
        Ps[w][lh * 4 + r][sub * 16 + lr] = f2bf(s[sub][r]);

    // PV: O += P (16x64) * V (64x64)
#pragma unroll
    for (int ks = 0; ks < 2; ++ks) {
      bf16x8 pa = *(const bf16x8*)&Ps[w][lr][ks * 32 + lh * 8];
#pragma unroll
      for (int n = 0; n < 4; ++n) {
        bf16x8 vb = *(const bf16x8*)&Vt[n * 16 + lr][ks * 32 + lh * 8];
        Oa[n] = mfma16x16x32(pa, vb, Oa[n]);
      }
    }
  }

  // epilogue: write attn out [B][T][H*64] bf16
  const int bb = bh / Hc, h = bh - bb * Hc;
#pragma unroll
  for (int n = 0; n < 4; ++n)
#pragma unroll
    for (int r = 0; r < 4; ++r) {
      const float val = Oa[n][r] / l_r[r];
      const int ti = q0 + w * 16 + lh * 4 + r;
      Out[((size_t)(bb * Tc + ti)) * 768 + h * 64 + n * 16 + lr] = f2bf(val);
    }
}

// -----------------------------------------------------------------------------
extern "C" void kernel_launch(void* const* d_in, const int* in_sizes, int n_in,
                              void* d_out, int out_size, void* d_ws, size_t ws_size,
                              hipStream_t stream) {
  (void)in_sizes; (void)n_in; (void)out_size; (void)ws_size;
  const float* x    = (const float*)d_in[0];
  const float* Wqkv = (const float*)d_in[1];
  const float* Wout = (const float*)d_in[2];
  float* out = (float*)d_out;

  u16* ws    = (u16*)d_ws;
  u16* xb    = ws;                     // 6291456 elems (x as bf16)
  u16* wqkvT = xb + 6291456;           // 1769472
  u16* woutT = wqkvT + 1769472;        // 589824
  u16* qws   = woutT + 589824;         // 6291456
  u16* kws   = qws + 6291456;          // 6291456
  u16* vws   = kws + 6291456;          // 6291456
  u16* aws   = xb;                     // attn out aliases xb (dead after gemm1)

  cvt_f32_to_bf16<<<6144, 256, 0, stream>>>(x, xb);
  transpose_cvt<<<dim3(36, 12), 256, 0, stream>>>(Wqkv, wqkvT, 768, 2304);
  transpose_cvt<<<dim3(12, 12), 256, 0, stream>>>(Wout, woutT, 768, 768);
  gemm_bt<0><<<dim3(18, 64), 256, 0, stream>>>(xb, wqkvT, qws, kws, vws, nullptr);
  swa_attn<<<dim3(32, 48), 256, 0, stream>>>(qws, kws, vws, aws);
  gemm_bt<1><<<dim3(6, 64), 256, 0, stream>>>(aws, woutT, nullptr, nullptr, nullptr, out);
}

// Round 8
// 107.668 us; speedup vs baseline: 1.3976x; 1.0285x over previous
//
#include <hip/hip_runtime.h>
#include <hip/hip_bf16.h>
#include <stdint.h>

typedef unsigned short u16;
typedef __attribute__((ext_vector_type(8))) short short8;
typedef __attribute__((ext_vector_type(8))) __bf16 bf16x8;
typedef __attribute__((ext_vector_type(4))) float f32x4;

constexpr int Bc  = 4;
constexpr int Tc  = 2048;
constexpr int Dc  = 768;
constexpr int Hc  = 12;
constexpr int WINc = 128;

static __device__ __forceinline__ u16 f2bf(float f) {
  union { float f; uint32_t u; } v; v.f = f;
  uint32_t u = v.u;
  return (u16)((u + 0x7fffu + ((u >> 16) & 1u)) >> 16);
}

static __device__ __forceinline__ f32x4 mfma16x16x32(bf16x8 a, bf16x8 b, f32x4 c) {
  return __builtin_amdgcn_mfma_f32_16x16x32_bf16(a, b, c, 0, 0, 0);
}

#define GLOAD_LDS16(gsrc, ldst)                                                \
  __builtin_amdgcn_global_load_lds(                                            \
      (const __attribute__((address_space(1))) void*)(gsrc),                   \
      (__attribute__((address_space(3))) void*)(ldst), 16, 0, 0)

// ------------------------------------------------------- fused prep kernel
// blocks [0,6144):       x f32 -> xb bf16 (vectorized)
// blocks [6144,6576):    Wqkv [768][2304] -> wqkvT [2304][768] bf16
// blocks [6576,6720):    Wout [768][768]  -> woutT [768][768] bf16
__global__ __launch_bounds__(256) void prep(const float* __restrict__ x,
                                            u16* __restrict__ xb,
                                            const float* __restrict__ Wqkv,
                                            u16* __restrict__ wqkvT,
                                            const float* __restrict__ Wout,
                                            u16* __restrict__ woutT) {
  __shared__ float tile[64][65];
  const int t = threadIdx.x;
  const int b = blockIdx.x;
  if (b < 6144) {
    const int i = b * 256 + t;
    const float4 f = ((const float4*)x)[i];
    union { u16 h[4]; uint2 u; } pk;
    pk.h[0] = f2bf(f.x); pk.h[1] = f2bf(f.y); pk.h[2] = f2bf(f.z); pk.h[3] = f2bf(f.w);
    ((uint2*)xb)[i] = pk.u;
    return;
  }
  const float* W; u16* WT; int C, bx, by;
  if (b < 6576) { W = Wqkv; WT = wqkvT; C = 2304; const int bb = b - 6144; bx = bb % 36; by = bb / 36; }
  else          { W = Wout; WT = woutT; C = 768;  const int bb = b - 6576; bx = bb % 12; by = bb / 12; }
  const int R = 768;
  const int c0 = bx * 64, r0 = by * 64;
#pragma unroll
  for (int i = 0; i < 16; ++i) {
    const int e = i * 256 + t;
    const int r = e >> 6, c = e & 63;
    tile[r][c] = W[(size_t)(r0 + r) * C + c0 + c];
  }
  __syncthreads();
#pragma unroll
  for (int i = 0; i < 16; ++i) {
    const int e = i * 256 + t;
    const int r = e >> 6, c = e & 63;
    WT[(size_t)(c0 + r) * R + r0 + c] = f2bf(tile[c][r]);
  }
}

// ---------------------------------------------------------------- GEMM  C = A * B^T
// BK=64, 12 K-steps; LDS [128][64] u16, XOR-swizzled on BOTH sides (R6-proven:
// 0 bank conflicts): linear gload_lds dest + inverse-swizzled global source;
// fragment reads apply the same XOR.
// EPI==0: q/k/v row-major [bh][t][64] coalesced (q pre-scaled by 0.125).
// EPI==1: write f32 to out [M][768].
template <int EPI>
__global__ __launch_bounds__(256) void gemm_bt(const u16* __restrict__ A,
                                               const u16* __restrict__ Bt,
                                               u16* __restrict__ q_ws,
                                               u16* __restrict__ k_ws,
                                               u16* __restrict__ v_ws,
                                               float* __restrict__ fout) {
  __shared__ u16 As[128][64];
  __shared__ u16 Bs[128][64];
  const int t  = threadIdx.x;
  const int w  = t >> 6, l = t & 63;
  const int lr = l & 15, lh = l >> 4;
  const int wm = w >> 1, wn = w & 1;
  const int m0 = blockIdx.y * 128, n0 = blockIdx.x * 128;

  f32x4 acc[4][4];
#pragma unroll
  for (int mi = 0; mi < 4; ++mi)
#pragma unroll
    for (int ni = 0; ni < 4; ++ni) acc[mi][ni] = f32x4{0.f, 0.f, 0.f, 0.f};

  const int srow = w * 8 + (l >> 3);
  const int scol = ((l & 7) ^ (l >> 3)) * 8;
  const u16* aP = A  + (size_t)(m0 + srow) * 768 + scol;
  const u16* bP = Bt + (size_t)(n0 + srow) * 768 + scol;
  char* asB = (char*)As + w * 1024;
  char* bsB = (char*)Bs + w * 1024;

  for (int kt = 0; kt < 12; ++kt) {
    const int ko = kt * 64;
    __syncthreads();
#pragma unroll
    for (int j = 0; j < 4; ++j) {
      GLOAD_LDS16(aP + ko + j * (32 * 768), asB + j * 4096);
      GLOAD_LDS16(bP + ko + j * (32 * 768), bsB + j * 4096);
    }
    __syncthreads();

#pragma unroll
    for (int kk = 0; kk < 2; ++kk) {
      const int cb = (kk * 64 + lh * 16) ^ ((lr & 7) << 4);
      bf16x8 af[4], bfr[4];
#pragma unroll
      for (int mi = 0; mi < 4; ++mi)
        af[mi] = *(const bf16x8*)((const char*)As + (wm * 64 + mi * 16 + lr) * 128 + cb);
#pragma unroll
      for (int ni = 0; ni < 4; ++ni)
        bfr[ni] = *(const bf16x8*)((const char*)Bs + (wn * 64 + ni * 16 + lr) * 128 + cb);
#pragma unroll
      for (int mi = 0; mi < 4; ++mi)
#pragma unroll
        for (int ni = 0; ni < 4; ++ni)
          acc[mi][ni] = mfma16x16x32(af[mi], bfr[ni], acc[mi][ni]);
    }
  }

  if (EPI == 0) {
#pragma unroll
    for (int mi = 0; mi < 4; ++mi)
#pragma unroll
      for (int ni = 0; ni < 4; ++ni) {
        const int col   = n0 + wn * 64 + ni * 16 + lr;
        const int which = col / 768;
        const int rem   = col - which * 768;
        const int h     = rem >> 6, d = rem & 63;
        u16* dst = (which == 0) ? q_ws : ((which == 1) ? k_ws : v_ws);
        const float scl = (which == 0) ? 0.125f : 1.0f;
#pragma unroll
        for (int r = 0; r < 4; ++r) {
          const int m  = m0 + wm * 64 + mi * 16 + lh * 4 + r;
          const int bb = m >> 11, tt = m & 2047;
          dst[(((size_t)(bb * Hc + h) * Tc + tt) << 6) + d] = f2bf(acc[mi][ni][r] * scl);
        }
      }
  } else {
#pragma unroll
    for (int mi = 0; mi < 4; ++mi)
#pragma unroll
      for (int ni = 0; ni < 4; ++ni) {
        const int col = n0 + wn * 64 + ni * 16 + lr;
#pragma unroll
        for (int r = 0; r < 4; ++r) {
          const int m = m0 + wm * 64 + mi * 16 + lh * 4 + r;
          fout[(size_t)m * 768 + col] = acc[mi][ni][r];
        }
      }
  }
}

// ----------------------------------------------- sliding-window flash attention
// Batch-staged: ALL (<=3) K/V tiles staged up front with every global load in
// flight simultaneously, then ONE __syncthreads, then barrier-free compute.
// Q fragments direct from global (wave-private). Ps wave-private (no barrier).
// Q/K/V ws: [bh][T][64] bf16 (q pre-scaled by 0.125). Out: [B][T][768] bf16.
__global__ __launch_bounds__(256) void swa_attn(const u16* __restrict__ Q,
                                                const u16* __restrict__ Kk,
                                                const u16* __restrict__ V,
                                                u16* __restrict__ Out) {
  __shared__ u16 Ks[3][64][72];
  __shared__ u16 Vt[3][64][72];   // Vt[ti][d][key]
  __shared__ u16 Ps[4][16][72];   // per-wave P tile

  const int t  = threadIdx.x;
  const int w  = t >> 6, l = t & 63;
  const int lr = l & 15, lh = l >> 4;
  const int bh = blockIdx.y;
  const int q0 = blockIdx.x * 64;
  const size_t head_base = (size_t)bh * Tc * 64;

  const int kb_lo = (q0 >= WINc) ? q0 - WINc : 0;
  const int nt    = ((q0 - kb_lo) >> 6) + 1;   // 1..3 tiles (block-uniform)

  // Q fragments direct from global: row q0 + w*16 + lr, k-chunk lh*8 / 32+lh*8
  const u16* qrow = Q + head_base + (size_t)(q0 + w * 16 + lr) * 64;
  const bf16x8 qa0 = *(const bf16x8*)(qrow + lh * 8);
  const bf16x8 qa1 = *(const bf16x8*)(qrow + 32 + lh * 8);

  // ---- issue ALL staging loads first (max memory-level parallelism)
  const int row = t >> 2, c = (t & 3) * 16;
  short8 kreg[3][2], vreg[3][2];
#pragma unroll
  for (int ti = 0; ti < 3; ++ti) {
    if (ti < nt) {
      const int kb = kb_lo + ti * 64;
      const short8* ksrc = (const short8*)(Kk + head_base + (size_t)(kb + row) * 64 + c);
      const short8* vsrc = (const short8*)(V  + head_base + (size_t)(kb + row) * 64 + c);
      kreg[ti][0] = ksrc[0]; kreg[ti][1] = ksrc[1];
      vreg[ti][0] = vsrc[0]; vreg[ti][1] = vsrc[1];
    }
  }
  // ---- write to LDS (K vectorized; V transposed via scalar writes)
#pragma unroll
  for (int ti = 0; ti < 3; ++ti) {
    if (ti < nt) {
      *(short8*)&Ks[ti][row][c]     = kreg[ti][0];
      *(short8*)&Ks[ti][row][c + 8] = kreg[ti][1];
#pragma unroll
      for (int j = 0; j < 8; ++j) {
        Vt[ti][c + j][row]     = (u16)vreg[ti][0][j];
        Vt[ti][c + 8 + j][row] = (u16)vreg[ti][1][j];
      }
    }
  }
  __syncthreads();   // the ONLY barrier

  float m_r[4], l_r[4];
  f32x4 Oa[4];
#pragma unroll
  for (int r = 0; r < 4; ++r) { m_r[r] = -1e30f; l_r[r] = 0.f; }
#pragma unroll
  for (int n = 0; n < 4; ++n) Oa[n] = f32x4{0.f, 0.f, 0.f, 0.f};

#pragma unroll
  for (int ti = 0; ti < 3; ++ti) {
    if (ti >= nt) break;
    const int kb = kb_lo + ti * 64;

    // ---- QK^T
    f32x4 s[4];
#pragma unroll
    for (int sub = 0; sub < 4; ++sub) {
      const bf16x8 kb0 = *(const bf16x8*)&Ks[ti][sub * 16 + lr][lh * 8];
      const bf16x8 kb1 = *(const bf16x8*)&Ks[ti][sub * 16 + lr][32 + lh * 8];
      f32x4 z = f32x4{0.f, 0.f, 0.f, 0.f};
      z = mfma16x16x32(qa0, kb0, z);
      z = mfma16x16x32(qa1, kb1, z);
      s[sub] = z;
    }

    // ---- mask (allowed: qi-128 <= kj <= qi); scale pre-folded into Q
    const int qbase = q0 + w * 16 + lh * 4;
#pragma unroll
    for (int sub = 0; sub < 4; ++sub) {
      const int kj = kb + sub * 16 + lr;
#pragma unroll
      for (int r = 0; r < 4; ++r) {
        const int qi = qbase + r;
        const bool ok = (kj <= qi) && (kj + WINc >= qi);
        s[sub][r] = ok ? s[sub][r] : -1e30f;
      }
    }

    // ---- online softmax (row = 16-lane lr-group reduce)
    float mt[4];
#pragma unroll
    for (int r = 0; r < 4; ++r)
      mt[r] = fmaxf(fmaxf(s[0][r], s[1][r]), fmaxf(s[2][r], s[3][r]));
#pragma unroll
    for (int msk = 1; msk < 16; msk <<= 1)
#pragma unroll
      for (int r = 0; r < 4; ++r)
        mt[r] = fmaxf(mt[r], __shfl_xor(mt[r], msk, 64));

    float al[4];
#pragma unroll
    for (int r = 0; r < 4; ++r) {
      const float mn = fmaxf(m_r[r], mt[r]);
      al[r] = __expf(m_r[r] - mn);
      m_r[r] = mn;
    }

    float rs[4] = {0.f, 0.f, 0.f, 0.f};
#pragma unroll
    for (int sub = 0; sub < 4; ++sub)
#pragma unroll
      for (int r = 0; r < 4; ++r) {
        const float p = __expf(s[sub][r] - m_r[r]);
        s[sub][r] = p;
        rs[r] += p;
      }
#pragma unroll
    for (int msk = 1; msk < 16; msk <<= 1)
#pragma unroll
      for (int r = 0; r < 4; ++r)
        rs[r] += __shfl_xor(rs[r], msk, 64);
#pragma unroll
    for (int r = 0; r < 4; ++r) l_r[r] = l_r[r] * al[r] + rs[r];

#pragma unroll
    for (int n = 0; n < 4; ++n)
#pragma unroll
      for (int r = 0; r < 4; ++r) Oa[n][r] *= al[r];

    // ---- P -> wave-private LDS (re-layout for PV A-operand)
#pragma unroll
    for (int sub = 0; sub < 4; ++sub)
#pragma unroll
      for (int r = 0; r < 4; ++r)
        Ps[w][lh * 4 + r][sub * 16 + lr] = f2bf(s[sub][r]);

    // ---- PV: O += P (16x64) * V (64x64)
#pragma unroll
    for (int ks = 0; ks < 2; ++ks) {
      const bf16x8 pa = *(const bf16x8*)&Ps[w][lr][ks * 32 + lh * 8];
#pragma unroll
      for (int n = 0; n < 4; ++n) {
        const bf16x8 vb = *(const bf16x8*)&Vt[ti][n * 16 + lr][ks * 32 + lh * 8];
        Oa[n] = mfma16x16x32(pa, vb, Oa[n]);
      }
    }
  }

  // ---- epilogue: attn out [B][T][H*64] bf16
  const int bb = bh / Hc, h = bh - bb * Hc;
#pragma unroll
  for (int r = 0; r < 4; ++r) {
    const float inv = 1.f / l_r[r];
    const int ti = q0 + w * 16 + lh * 4 + r;
#pragma unroll
    for (int n = 0; n < 4; ++n)
      Out[((size_t)(bb * Tc + ti)) * 768 + h * 64 + n * 16 + lr] =
          f2bf(Oa[n][r] * inv);
  }
}

// -----------------------------------------------------------------------------
extern "C" void kernel_launch(void* const* d_in, const int* in_sizes, int n_in,
                              void* d_out, int out_size, void* d_ws, size_t ws_size,
                              hipStream_t stream) {
  (void)in_sizes; (void)n_in; (void)out_size; (void)ws_size;
  const float* x    = (const float*)d_in[0];
  const float* Wqkv = (const float*)d_in[1];
  const float* Wout = (const float*)d_in[2];
  float* out = (float*)d_out;

  u16* ws    = (u16*)d_ws;
  u16* xb    = ws;                     // 6291456 elems (x as bf16)
  u16* wqkvT = xb + 6291456;           // 1769472
  u16* woutT = wqkvT + 1769472;        // 589824
  u16* qws   = woutT + 589824;         // 6291456
  u16* kws   = qws + 6291456;          // 6291456
  u16* vws   = kws + 6291456;          // 6291456
  u16* aws   = xb;                     // attn out aliases xb (dead after gemm1)

  prep<<<6720, 256, 0, stream>>>(x, xb, Wqkv, wqkvT, Wout, woutT);
  gemm_bt<0><<<dim3(18, 64), 256, 0, stream>>>(xb, wqkvT, qws, kws, vws, nullptr);
  swa_attn<<<dim3(32, 48), 256, 0, stream>>>(qws, kws, vws, aws);
  gemm_bt<1><<<dim3(6, 64), 256, 0, stream>>>(aws, woutT, nullptr, nullptr, nullptr, out);
}